// Round 1
// baseline (711.074 us; speedup 1.0000x reference)
//
#include <hip/hip_runtime.h>
#include <math.h>

// Problem constants (B,S,H fixed by reference setup_inputs)
#define BB 32
#define SS 4096
#define HH 1024
#define NCHUNK 16               // S-chunks per batch -> grid 16*32=512 blocks (2/CU)
#define CHUNK (SS / NCHUNK)     // 256 s-rows per block, 64 per wave
#define NEG_INF9 (-1.0e9f)

__device__ __forceinline__ float wave_reduce_sum(float v) {
#pragma unroll
    for (int off = 32; off > 0; off >>= 1) v += __shfl_xor(v, off, 64);
    return v;
}

// ---------------- Kernel 1: q = query @ W^T  (per b: [H] = [H] x [H,H]) ----------------
// W rows are L2-resident (4 MB); wave-cooperative dot, coalesced float4 loads.
__global__ __launch_bounds__(256) void qproj_kernel(const float* __restrict__ query,
                                                    const float* __restrict__ W,
                                                    float* __restrict__ q) {
    const int b    = blockIdx.y;
    const int wave = threadIdx.x >> 6;
    const int lane = threadIdx.x & 63;

    const float4* qp = (const float4*)(query + (size_t)b * HH);
    float4 qv[4];
#pragma unroll
    for (int r = 0; r < 4; ++r) qv[r] = qp[r * 64 + lane];

    const int obase = blockIdx.x * 128 + wave * 32;
    for (int i = 0; i < 32; ++i) {
        const int o = obase + i;
        const float4* wp = (const float4*)(W + (size_t)o * HH);
        float acc = 0.f;
#pragma unroll
        for (int r = 0; r < 4; ++r) {
            const float4 wv = wp[r * 64 + lane];
            acc += wv.x * qv[r].x + wv.y * qv[r].y + wv.z * qv[r].z + wv.w * qv[r].w;
        }
        acc = wave_reduce_sum(acc);
        if (lane == 0) q[(size_t)b * HH + o] = acc;
    }
}

// ---------------- Kernel 2: flash-style fused scores+softmax+context partials ----------------
// One block per (chunk c, batch b). Each wave streams 64 key rows: dot -> online softmax
// -> accumulate O with the SAME key fragment already in registers (keys read exactly once).
__global__ __launch_bounds__(256) void attn_chunk_kernel(const float* __restrict__ q,
                                                         const float* __restrict__ keys,
                                                         const int* __restrict__ mask,
                                                         float* __restrict__ raw_scores, // d_out weights region
                                                         float* __restrict__ pm,
                                                         float* __restrict__ pl,
                                                         float* __restrict__ pO) {
    const int b    = blockIdx.y;
    const int c    = blockIdx.x;
    const int wave = threadIdx.x >> 6;
    const int lane = threadIdx.x & 63;

    const float4* qp = (const float4*)(q + (size_t)b * HH);
    float4 qv[4];
#pragma unroll
    for (int r = 0; r < 4; ++r) qv[r] = qp[r * 64 + lane];

    float m = -INFINITY;
    float l = 0.f;
    float4 acc[4];
#pragma unroll
    for (int r = 0; r < 4; ++r) acc[r] = make_float4(0.f, 0.f, 0.f, 0.f);

    const int s0 = c * CHUNK;
    for (int t = wave; t < CHUNK; t += 4) {
        const int s = s0 + t;
        const float4* kp = (const float4*)(keys + ((size_t)b * SS + s) * HH);
        float4 kv[4];
#pragma unroll
        for (int r = 0; r < 4; ++r) kv[r] = kp[r * 64 + lane];  // 64 lanes x 16B = 1KB coalesced

        float sc = 0.f;
#pragma unroll
        for (int r = 0; r < 4; ++r)
            sc += kv[r].x * qv[r].x + kv[r].y * qv[r].y + kv[r].z * qv[r].z + kv[r].w * qv[r].w;
        sc = wave_reduce_sum(sc);  // all lanes hold the score

        if (mask[(size_t)b * SS + s] != 0) sc = NEG_INF9;
        if (lane == 0) raw_scores[(size_t)b * SS + s] = sc;

        const float mnew  = fmaxf(m, sc);
        const float scale = __expf(m - mnew);   // m=-inf first iter -> exp(-inf)=0
        const float p     = __expf(sc - mnew);
        l = l * scale + p;
#pragma unroll
        for (int r = 0; r < 4; ++r) {
            acc[r].x = acc[r].x * scale + p * kv[r].x;
            acc[r].y = acc[r].y * scale + p * kv[r].y;
            acc[r].z = acc[r].z * scale + p * kv[r].z;
            acc[r].w = acc[r].w * scale + p * kv[r].w;
        }
        m = mnew;
    }

    // combine the 4 waves of this block via LDS
    __shared__ float  sm[4];
    __shared__ float  sl[4];
    __shared__ float4 sO[4][256];  // 16 KB
#pragma unroll
    for (int r = 0; r < 4; ++r) sO[wave][r * 64 + lane] = acc[r];
    if (lane == 0) { sm[wave] = m; sl[wave] = l; }
    __syncthreads();

    const float M = fmaxf(fmaxf(sm[0], sm[1]), fmaxf(sm[2], sm[3]));
    float f[4];
#pragma unroll
    for (int w = 0; w < 4; ++w) f[w] = __expf(sm[w] - M);
    const float L = sl[0] * f[0] + sl[1] * f[1] + sl[2] * f[2] + sl[3] * f[3];

    const int tid = threadIdx.x;
    float4 o = make_float4(0.f, 0.f, 0.f, 0.f);
#pragma unroll
    for (int w = 0; w < 4; ++w) {
        const float4 v = sO[w][tid];
        o.x += f[w] * v.x; o.y += f[w] * v.y; o.z += f[w] * v.z; o.w += f[w] * v.w;
    }
    ((float4*)(pO + ((size_t)b * NCHUNK + c) * HH))[tid] = o;
    if (tid == 0) { pm[b * NCHUNK + c] = M; pl[b * NCHUNK + c] = L; }
}

// ---------------- Kernel 3: merge chunk partials -> context; normalize weights in place ----------------
__global__ __launch_bounds__(256) void combine_kernel(const float* __restrict__ pm,
                                                      const float* __restrict__ pl,
                                                      const float* __restrict__ pO,
                                                      float* __restrict__ context,
                                                      float* __restrict__ weights) {
    const int b   = blockIdx.x;
    const int tid = threadIdx.x;

    float M = -INFINITY;
#pragma unroll
    for (int c = 0; c < NCHUNK; ++c) M = fmaxf(M, pm[b * NCHUNK + c]);
    float fc[NCHUNK];
    float L = 0.f;
#pragma unroll
    for (int c = 0; c < NCHUNK; ++c) {
        fc[c] = __expf(pm[b * NCHUNK + c] - M);
        L += pl[b * NCHUNK + c] * fc[c];
    }
    const float invL = 1.f / L;

    float4 o = make_float4(0.f, 0.f, 0.f, 0.f);
#pragma unroll
    for (int c = 0; c < NCHUNK; ++c) {
        const float4 v = ((const float4*)(pO + ((size_t)b * NCHUNK + c) * HH))[tid];
        const float g = fc[c] * invL;
        o.x += g * v.x; o.y += g * v.y; o.z += g * v.z; o.w += g * v.w;
    }
    ((float4*)(context + (size_t)b * HH))[tid] = o;

    for (int s = tid; s < SS; s += 256) {
        const float sc = weights[(size_t)b * SS + s];
        weights[(size_t)b * SS + s] = __expf(sc - M) * invL;  // masked -1e9 -> exactly 0
    }
}

extern "C" void kernel_launch(void* const* d_in, const int* in_sizes, int n_in,
                              void* d_out, int out_size, void* d_ws, size_t ws_size,
                              hipStream_t stream) {
    const float* query = (const float*)d_in[0];  // [B,1,H]
    const float* keys  = (const float*)d_in[1];  // [B,S,H]
    const int*   mask  = (const int*)d_in[2];    // [B,S] bool->int
    const float* W     = (const float*)d_in[3];  // [H,H]

    float* context = (float*)d_out;                     // B*H floats
    float* weights = (float*)d_out + (size_t)BB * HH;   // B*S floats

    float* q  = (float*)d_ws;                    // B*H
    float* pm = q + (size_t)BB * HH;             // B*NCHUNK
    float* pl = pm + BB * NCHUNK;                // B*NCHUNK
    float* pO = pl + BB * NCHUNK;                // B*NCHUNK*H  (~2.1 MB total ws)

    qproj_kernel<<<dim3(HH / 128, BB), 256, 0, stream>>>(query, W, q);
    attn_chunk_kernel<<<dim3(NCHUNK, BB), 256, 0, stream>>>(q, keys, mask, weights, pm, pl, pO);
    combine_kernel<<<BB, 256, 0, stream>>>(pm, pl, pO, context, weights);
}